// Round 2
// baseline (1890.202 us; speedup 1.0000x reference)
//
#include <hip/hip_runtime.h>
#include <math.h>

#define N_NODES 10000
#define N_EDGES 160000
#define F 128
#define NB 8
#define HR 64
#define NSPEC 10
#define PI_F 3.14159265358979323846f

__device__ __forceinline__ float silu_f(float x){ return x / (1.f + expf(-x)); }

// ---------------- edge precompute: sh[E,16], basis[E,8], receiver histogram ----------------
__global__ void k_edge_pre(const float* __restrict__ vec, const int* __restrict__ recv,
                           float* __restrict__ sh, float* __restrict__ basis, int* __restrict__ counts)
{
    int e = blockIdx.x * 256 + threadIdx.x;
    if (e >= N_EDGES) return;
    float x = vec[e*3+0], y = vec[e*3+1], z = vec[e*3+2];
    float r = sqrtf(x*x + y*y + z*z);
    r = fmaxf(r, 1e-9f);
    float inv = 1.f / r;
    x *= inv; y *= inv; z *= inv;
    const float s3=1.7320508075688772f, s5=2.23606797749979f, s7=2.6457513110645907f,
                s15=3.872983346207417f, s42=6.480740698407860f, s70=8.366600265340756f,
                s105=10.246950765959598f;
    float* S = sh + (size_t)e*16;
    S[0]=1.f; S[1]=s3*x; S[2]=s3*y; S[3]=s3*z;
    S[4]=s15*x*y; S[5]=s15*y*z; S[6]=0.5f*s5*(3.f*z*z-1.f); S[7]=s15*x*z;
    S[8]=0.5f*s15*(x*x-y*y);
    S[9]=0.25f*s70*y*(3.f*x*x-y*y); S[10]=s105*x*y*z; S[11]=0.25f*s42*y*(5.f*z*z-1.f);
    S[12]=0.5f*s7*(5.f*z*z*z-3.f*z); S[13]=0.25f*s42*x*(5.f*z*z-1.f);
    S[14]=0.5f*s105*z*(x*x-y*y); S[15]=0.25f*s70*x*(x*x-3.f*y*y);
    float rc = fminf(r, 5.0f);
    float cut = 0.5f * (cosf(PI_F * rc * 0.2f) + 1.f);
    float pref = sqrtf(0.4f) * cut / r;
    float* B = basis + (size_t)e*8;
    #pragma unroll
    for (int k = 1; k <= 8; ++k) B[k-1] = pref * sinf(PI_F * 0.2f * (float)k * r);
    atomicAdd(&counts[recv[e]], 1);
}

// ---------------- block-wide scan -> row_ptr ----------------
__global__ void k_scan(const int* __restrict__ counts, int* __restrict__ row_ptr)
{
    __shared__ int ps[1024];
    const int t = threadIdx.x;
    int base = t * 10;
    int loc[10];
    int sum = 0;
    #pragma unroll
    for (int j = 0; j < 10; ++j) {
        int idx = base + j;
        int c = (idx < N_NODES) ? counts[idx] : 0;
        loc[j] = c; sum += c;
    }
    ps[t] = sum;
    __syncthreads();
    for (int off = 1; off < 1024; off <<= 1) {
        int v = (t >= off) ? ps[t-off] : 0;
        __syncthreads();
        ps[t] += v;
        __syncthreads();
    }
    int ex = ps[t] - sum;
    #pragma unroll
    for (int j = 0; j < 10; ++j) {
        int idx = base + j;
        if (idx < N_NODES) row_ptr[idx] = ex;
        ex += loc[j];
    }
    if (t == 1023) row_ptr[N_NODES] = ex;
}

// ---------------- fill CSR edge list ----------------
__global__ void k_fill(const int* __restrict__ recv, const int* __restrict__ row_ptr,
                       int* __restrict__ cursor, int* __restrict__ elist)
{
    int e = blockIdx.x * 256 + threadIdx.x;
    if (e >= N_EDGES) return;
    int r = recv[e];
    int pos = atomicAdd(&cursor[r], 1);
    elist[row_ptr[r] + pos] = e;
}

// ---------------- init feats (N,F,16) and scalA (N,F) ----------------
__global__ void k_init(const int* __restrict__ spec, const float* __restrict__ embW,
                       float* __restrict__ feats, float* __restrict__ scalA)
{
    int tid = blockIdx.x * 256 + threadIdx.x;
    if (tid >= N_NODES * F * 16) return;
    int n = tid >> 11; int q = tid & 2047; int f = q >> 4; int m = q & 15;
    float v = 0.f;
    if (m == 0) { v = embW[spec[n]*F + f]; scalA[n*F + f] = v; }
    feats[tid] = v;
}

// ---------------- fused per-node layer kernel ----------------
// one 256-thread block per node; thread t handles channel f=t&127, m-half mh=t>>7 (8 m's)
__global__ __launch_bounds__(256) void k_layer(
    const int layer,
    const int* __restrict__ spec_arr,
    const int* __restrict__ senders,
    const int* __restrict__ row_ptr,
    const int* __restrict__ elist,
    const float* __restrict__ sh,
    const float* __restrict__ basis,
    const float* __restrict__ rW1,
    const float* __restrict__ rb1,
    const float* __restrict__ rW2,
    const float* __restrict__ linW,
    const float* __restrict__ prodc,
    const float* __restrict__ scW,
    const float* __restrict__ ro0,
    const float* __restrict__ ro1W1,
    const float* __restrict__ ro1W2,
    const float* __restrict__ scal_in,
    float* __restrict__ scal_out,
    float* __restrict__ feats,
    float* __restrict__ out)
{
    __shared__ float W1s[NB*HR];
    __shared__ float b1s[HR];
    __shared__ float hS[HR];
    __shared__ float rwS[4*F];
    __shared__ float sS[F];
    __shared__ float shS[16];
    __shared__ float basS[NB];
    __shared__ float aggS[F*17];
    __shared__ float polyS[F];
    __shared__ float scalS[F];
    __shared__ float redS[F];

    const int t = threadIdx.x;
    const int n = blockIdx.x;
    const int f = t & 127;
    const int mh = t >> 7;

    // radial W1/b1 -> LDS (f32)
    W1s[t] = rW1[layer*NB*HR + t];
    W1s[256 + t] = rW1[layer*NB*HR + 256 + t];
    if (t < HR) b1s[t] = rb1[layer*HR + t];

    // radial W2 columns (2t, 2t+1) -> registers
    const float2* W2g = (const float2*)(rW2 + (size_t)layer*HR*512);
    float2 w2r[64];
    #pragma unroll
    for (int j = 0; j < 64; ++j) w2r[j] = W2g[j*256 + t];

    float acc[8] = {0,0,0,0,0,0,0,0};
    const int istart = row_ptr[n], iend = row_ptr[n+1];
    __syncthreads();

    for (int ii = istart; ii < iend; ++ii) {
        const int e = elist[ii];
        __syncthreads();                                 // (a) prev iter LDS reads done
        if (t < 16)                 shS[t]      = sh[(size_t)e*16 + t];
        else if (t < 24)            basS[t-16]  = basis[(size_t)e*8 + (t-16)];
        if (t >= 64 && t < 192)     sS[t-64]    = scal_in[(size_t)senders[e]*F + (t-64)];
        __syncthreads();                                 // (b)
        if (t < HR) {
            float a = b1s[t];
            #pragma unroll
            for (int k = 0; k < NB; ++k) a = fmaf(basS[k], W1s[k*HR + t], a);
            hS[t] = a / (1.f + expf(-a));
        }
        __syncthreads();                                 // (c)
        float r0 = 0.f, r1 = 0.f;
        #pragma unroll
        for (int j = 0; j < 64; ++j) {
            float hj = hS[j];
            r0 = fmaf(hj, w2r[j].x, r0);
            r1 = fmaf(hj, w2r[j].y, r1);
        }
        {
            int ff = t >> 1; int lb = (t & 1) * 2;       // col 2t -> (f=t>>1, l=lb)
            rwS[lb*F + ff]     = r0;
            rwS[(lb+1)*F + ff] = r1;
        }
        __syncthreads();                                 // (d)
        {
            float sf  = sS[f];
            float rl0 = rwS[f], rl1 = rwS[F+f], rl2 = rwS[2*F+f], rl3 = rwS[3*F+f];
            if (mh == 0) {   // m = 0..7, l = [0,1,1,1,2,2,2,2]
                acc[0] = fmaf(sf*rl0, shS[0], acc[0]);
                acc[1] = fmaf(sf*rl1, shS[1], acc[1]);
                acc[2] = fmaf(sf*rl1, shS[2], acc[2]);
                acc[3] = fmaf(sf*rl1, shS[3], acc[3]);
                acc[4] = fmaf(sf*rl2, shS[4], acc[4]);
                acc[5] = fmaf(sf*rl2, shS[5], acc[5]);
                acc[6] = fmaf(sf*rl2, shS[6], acc[6]);
                acc[7] = fmaf(sf*rl2, shS[7], acc[7]);
            } else {         // m = 8..15, l = [2,3,3,3,3,3,3,3]
                acc[0] = fmaf(sf*rl2, shS[8],  acc[0]);
                acc[1] = fmaf(sf*rl3, shS[9],  acc[1]);
                acc[2] = fmaf(sf*rl3, shS[10], acc[2]);
                acc[3] = fmaf(sf*rl3, shS[11], acc[3]);
                acc[4] = fmaf(sf*rl3, shS[12], acc[4]);
                acc[5] = fmaf(sf*rl3, shS[13], acc[5]);
                acc[6] = fmaf(sf*rl3, shS[14], acc[6]);
                acc[7] = fmaf(sf*rl3, shS[15], acc[7]);
            }
        }
    }

    __syncthreads();
    #pragma unroll
    for (int j = 0; j < 8; ++j) aggS[f*17 + mh*8 + j] = acc[j];
    __syncthreads();

    const int spec = spec_arr[n];
    const float* Wl = linW + (((size_t)layer*NSPEC + spec)*4) * F * F;

    float nv[8] = {0,0,0,0,0,0,0,0};
    if (mh == 0) {
        for (int f2 = 0; f2 < F; ++f2) {
            const float* ag = &aggS[f2*17];
            float w0  = Wl[(0*F + f2)*F + f];
            float w1  = Wl[(1*F + f2)*F + f];
            float w2v = Wl[(2*F + f2)*F + f];
            nv[0] = fmaf(ag[0], w0,  nv[0]);
            nv[1] = fmaf(ag[1], w1,  nv[1]);
            nv[2] = fmaf(ag[2], w1,  nv[2]);
            nv[3] = fmaf(ag[3], w1,  nv[3]);
            nv[4] = fmaf(ag[4], w2v, nv[4]);
            nv[5] = fmaf(ag[5], w2v, nv[5]);
            nv[6] = fmaf(ag[6], w2v, nv[6]);
            nv[7] = fmaf(ag[7], w2v, nv[7]);
        }
    } else {
        for (int f2 = 0; f2 < F; ++f2) {
            const float* ag = &aggS[f2*17 + 8];
            float w2v = Wl[(2*F + f2)*F + f];
            float w3  = Wl[(3*F + f2)*F + f];
            nv[0] = fmaf(ag[0], w2v, nv[0]);
            nv[1] = fmaf(ag[1], w3,  nv[1]);
            nv[2] = fmaf(ag[2], w3,  nv[2]);
            nv[3] = fmaf(ag[3], w3,  nv[3]);
            nv[4] = fmaf(ag[4], w3,  nv[4]);
            nv[5] = fmaf(ag[5], w3,  nv[5]);
            nv[6] = fmaf(ag[6], w3,  nv[6]);
            nv[7] = fmaf(ag[7], w3,  nv[7]);
        }
    }
    #pragma unroll
    for (int j = 0; j < 8; ++j) nv[j] *= 0.5f;  // EPS

    if (mh == 0) polyS[f] = nv[0];
    __syncthreads();
    const float* pc = prodc + ((size_t)layer*NSPEC + spec)*3*F;
    float sg = polyS[f];
    float poly = pc[f] + pc[F+f]*sg + pc[2*F+f]*sg*sg;

    float scv[8] = {0,0,0,0,0,0,0,0};
    if (layer > 0) {
        __syncthreads();  // all lin reads of aggS done
        {   // load old feats[n] -> aggS (padded layout), coalesced float4
            const float4* fp = (const float4*)(feats + (size_t)n*2048);
            float4 a = fp[t*2], b = fp[t*2 + 1];
            float tmp[8] = {a.x,a.y,a.z,a.w,b.x,b.y,b.z,b.w};
            #pragma unroll
            for (int k = 0; k < 8; ++k) {
                int q = t*8 + k;
                aggS[(q >> 4)*17 + (q & 15)] = tmp[k];
            }
        }
        __syncthreads();
        const float* Ws = scW + (((size_t)layer*NSPEC + spec)*4) * F * F;
        if (mh == 0) {
            for (int f2 = 0; f2 < F; ++f2) {
                const float* ag = &aggS[f2*17];
                float w0  = Ws[(0*F + f2)*F + f];
                float w1  = Ws[(1*F + f2)*F + f];
                float w2v = Ws[(2*F + f2)*F + f];
                scv[0] = fmaf(ag[0], w0,  scv[0]);
                scv[1] = fmaf(ag[1], w1,  scv[1]);
                scv[2] = fmaf(ag[2], w1,  scv[2]);
                scv[3] = fmaf(ag[3], w1,  scv[3]);
                scv[4] = fmaf(ag[4], w2v, scv[4]);
                scv[5] = fmaf(ag[5], w2v, scv[5]);
                scv[6] = fmaf(ag[6], w2v, scv[6]);
                scv[7] = fmaf(ag[7], w2v, scv[7]);
            }
        } else {
            for (int f2 = 0; f2 < F; ++f2) {
                const float* ag = &aggS[f2*17 + 8];
                float w2v = Ws[(2*F + f2)*F + f];
                float w3  = Ws[(3*F + f2)*F + f];
                scv[0] = fmaf(ag[0], w2v, scv[0]);
                scv[1] = fmaf(ag[1], w3,  scv[1]);
                scv[2] = fmaf(ag[2], w3,  scv[2]);
                scv[3] = fmaf(ag[3], w3,  scv[3]);
                scv[4] = fmaf(ag[4], w3,  scv[4]);
                scv[5] = fmaf(ag[5], w3,  scv[5]);
                scv[6] = fmaf(ag[6], w3,  scv[6]);
                scv[7] = fmaf(ag[7], w3,  scv[7]);
            }
        }
    }

    float ov[8];
    #pragma unroll
    for (int j = 0; j < 8; ++j) ov[j] = fmaf(nv[j], poly, scv[j]);

    {   // write new feats[n, f, mh*8 + 0..7]
        float4* wp = (float4*)(feats + (size_t)n*2048 + f*16 + mh*8);
        wp[0] = make_float4(ov[0], ov[1], ov[2], ov[3]);
        wp[1] = make_float4(ov[4], ov[5], ov[6], ov[7]);
    }
    if (mh == 0) { scal_out[n*F + f] = ov[0]; scalS[f] = ov[0]; }
    __syncthreads();

    if (layer == 0) {
        if (t < 128) redS[t] = scalS[t] * ro0[t];
        __syncthreads();
        for (int off = 64; off > 0; off >>= 1) {
            if (t < off) redS[t] += redS[t + off];
            __syncthreads();
        }
        if (t == 0) out[n*2 + 0] = redS[0];
    } else {
        if (t < 16) {
            float a = 0.f;
            for (int g = 0; g < F; ++g) a = fmaf(scalS[g], ro1W1[g*16 + t], a);
            a = silu_f(a);
            redS[t] = a * ro1W2[t];
        }
        __syncthreads();
        if (t == 0) {
            float s2 = 0.f;
            #pragma unroll
            for (int j = 0; j < 16; ++j) s2 += redS[j];
            out[n*2 + 1] = s2;
        }
    }
}

extern "C" void kernel_launch(void* const* d_in, const int* in_sizes, int n_in,
                              void* d_out, int out_size, void* d_ws, size_t ws_size,
                              hipStream_t stream)
{
    (void)in_sizes; (void)n_in; (void)out_size; (void)ws_size;
    const float* vectors   = (const float*)d_in[0];
    const int*   spec      = (const int*)d_in[1];
    const int*   senders   = (const int*)d_in[2];
    const int*   receivers = (const int*)d_in[3];
    const float* embW      = (const float*)d_in[4];
    const float* rW1       = (const float*)d_in[5];
    const float* rb1       = (const float*)d_in[6];
    const float* rW2       = (const float*)d_in[7];
    const float* linW      = (const float*)d_in[8];
    const float* prodc     = (const float*)d_in[9];
    const float* scW       = (const float*)d_in[10];
    const float* ro0       = (const float*)d_in[11];
    const float* ro1W1     = (const float*)d_in[12];
    const float* ro1W2     = (const float*)d_in[13];
    float* out = (float*)d_out;

    char* ws = (char*)d_ws;
    float* sh      = (float*)ws; ws += sizeof(float)*(size_t)N_EDGES*16;
    float* basis   = (float*)ws; ws += sizeof(float)*(size_t)N_EDGES*8;
    float* scalA   = (float*)ws; ws += sizeof(float)*(size_t)N_NODES*F;
    float* scalB   = (float*)ws; ws += sizeof(float)*(size_t)N_NODES*F;
    float* feats   = (float*)ws; ws += sizeof(float)*(size_t)N_NODES*F*16;
    int*   row_ptr = (int*)ws;   ws += sizeof(int)*(N_NODES+1);
    int*   counts  = (int*)ws;   ws += sizeof(int)*N_NODES;
    int*   cursor  = (int*)ws;   ws += sizeof(int)*N_NODES;
    int*   elist   = (int*)ws;   ws += sizeof(int)*N_EDGES;

    hipMemsetAsync(counts, 0, sizeof(int)*2*N_NODES, stream);  // counts + cursor (contiguous)

    k_edge_pre<<<(N_EDGES+255)/256, 256, 0, stream>>>(vectors, receivers, sh, basis, counts);
    k_scan<<<1, 1024, 0, stream>>>(counts, row_ptr);
    k_fill<<<(N_EDGES+255)/256, 256, 0, stream>>>(receivers, row_ptr, cursor, elist);
    k_init<<<(N_NODES*F*16+255)/256, 256, 0, stream>>>(spec, embW, feats, scalA);

    k_layer<<<N_NODES, 256, 0, stream>>>(0, spec, senders, row_ptr, elist, sh, basis,
        rW1, rb1, rW2, linW, prodc, scW, ro0, ro1W1, ro1W2, scalA, scalB, feats, out);
    k_layer<<<N_NODES, 256, 0, stream>>>(1, spec, senders, row_ptr, elist, sh, basis,
        rW1, rb1, rW2, linW, prodc, scW, ro0, ro1W1, ro1W2, scalB, scalA, feats, out);
}

// Round 4
// 1264.192 us; speedup vs baseline: 1.4952x; 1.4952x over previous
//
#include <hip/hip_runtime.h>
#include <math.h>
#include <stdint.h>

#define N_NODES 10000
#define N_EDGES 160000
#define F 128
#define NB 8
#define HR 64
#define NSPEC 10
#define PI_F 3.14159265358979323846f
#define CHUNK 4

__device__ __forceinline__ float silu_f(float x){ return x / (1.f + expf(-x)); }

// ---------------- edge precompute: sh[E,16], basis[E,8], receiver histogram ----------------
__global__ void k_edge_pre(const float* __restrict__ vec, const int* __restrict__ recv,
                           float* __restrict__ sh, float* __restrict__ basis, int* __restrict__ counts)
{
    int e = blockIdx.x * 256 + threadIdx.x;
    if (e >= N_EDGES) return;
    float x = vec[e*3+0], y = vec[e*3+1], z = vec[e*3+2];
    float r = sqrtf(x*x + y*y + z*z);
    r = fmaxf(r, 1e-9f);
    float inv = 1.f / r;
    x *= inv; y *= inv; z *= inv;
    const float s3=1.7320508075688772f, s5=2.23606797749979f, s7=2.6457513110645907f,
                s15=3.872983346207417f, s42=6.480740698407860f, s70=8.366600265340756f,
                s105=10.246950765959598f;
    float* S = sh + (size_t)e*16;
    S[0]=1.f; S[1]=s3*x; S[2]=s3*y; S[3]=s3*z;
    S[4]=s15*x*y; S[5]=s15*y*z; S[6]=0.5f*s5*(3.f*z*z-1.f); S[7]=s15*x*z;
    S[8]=0.5f*s15*(x*x-y*y);
    S[9]=0.25f*s70*y*(3.f*x*x-y*y); S[10]=s105*x*y*z; S[11]=0.25f*s42*y*(5.f*z*z-1.f);
    S[12]=0.5f*s7*(5.f*z*z*z-3.f*z); S[13]=0.25f*s42*x*(5.f*z*z-1.f);
    S[14]=0.5f*s105*z*(x*x-y*y); S[15]=0.25f*s70*x*(x*x-3.f*y*y);
    float rc = fminf(r, 5.0f);
    float cut = 0.5f * (cosf(PI_F * rc * 0.2f) + 1.f);
    float pref = sqrtf(0.4f) * cut / r;
    float* B = basis + (size_t)e*8;
    #pragma unroll
    for (int k = 1; k <= 8; ++k) B[k-1] = pref * sinf(PI_F * 0.2f * (float)k * r);
    atomicAdd(&counts[recv[e]], 1);
}

// ---------------- block-wide scan -> row_ptr ----------------
__global__ void k_scan(const int* __restrict__ counts, int* __restrict__ row_ptr)
{
    __shared__ int ps[1024];
    const int t = threadIdx.x;
    int base = t * 10;
    int loc[10];
    int sum = 0;
    #pragma unroll
    for (int j = 0; j < 10; ++j) {
        int idx = base + j;
        int c = (idx < N_NODES) ? counts[idx] : 0;
        loc[j] = c; sum += c;
    }
    ps[t] = sum;
    __syncthreads();
    for (int off = 1; off < 1024; off <<= 1) {
        int v = (t >= off) ? ps[t-off] : 0;
        __syncthreads();
        ps[t] += v;
        __syncthreads();
    }
    int ex = ps[t] - sum;
    #pragma unroll
    for (int j = 0; j < 10; ++j) {
        int idx = base + j;
        if (idx < N_NODES) row_ptr[idx] = ex;
        ex += loc[j];
    }
    if (t == 1023) row_ptr[N_NODES] = ex;
}

// ---------------- fill CSR edge list ----------------
__global__ void k_fill(const int* __restrict__ recv, const int* __restrict__ row_ptr,
                       int* __restrict__ cursor, int* __restrict__ elist)
{
    int e = blockIdx.x * 256 + threadIdx.x;
    if (e >= N_EDGES) return;
    int r = recv[e];
    int pos = atomicAdd(&cursor[r], 1);
    elist[row_ptr[r] + pos] = e;
}

// ---------------- init scalA (N,F) = emb ----------------
__global__ void k_init_scal(const int* __restrict__ spec, const float* __restrict__ embW,
                            float* __restrict__ scalA)
{
    int tid = blockIdx.x * 256 + threadIdx.x;
    if (tid >= N_NODES * F) return;
    int n = tid >> 7, f = tid & 127;
    scalA[tid] = embW[spec[n]*F + f];
}

// ---------------- radial MLP over CSR-position window of one node-chunk ----------------
// positions p in [row_ptr[n0], row_ptr[n1]); rw slot = p - row_ptr[n0]
// 256 threads; thread t owns output cols (2t, 2t+1); 4 positions per block-iteration
__global__ __launch_bounds__(256) void k_radial(
    const int layer, const int n0, const int n1, const int cap,
    const int* __restrict__ row_ptr,
    const int* __restrict__ elist,
    const float* __restrict__ basis,
    const float* __restrict__ rW1,
    const float* __restrict__ rb1,
    const float* __restrict__ rW2,
    float* __restrict__ rw)
{
    __shared__ float W1s[NB*HR];
    __shared__ float b1s[HR];
    __shared__ float hS[CHUNK][HR];

    const int t = threadIdx.x;
    W1s[t] = rW1[layer*NB*HR + t];
    W1s[256 + t] = rW1[layer*NB*HR + 256 + t];
    if (t < HR) b1s[t] = rb1[layer*HR + t];

    const float2* W2g = (const float2*)(rW2 + (size_t)layer*HR*512);
    float2 w2r[64];
    #pragma unroll
    for (int j = 0; j < 64; ++j) w2r[j] = W2g[j*256 + t];

    const int p0   = row_ptr[n0];
    const int pend = row_ptr[n1];
    const int e4 = t >> 6, j = t & 63;
    float2* rw2p = (float2*)rw;
    const int stride = gridDim.x * CHUNK;

    __syncthreads();
    for (int base = p0 + blockIdx.x * CHUNK; base < pend; base += stride) {
        const int p = base + e4;
        // ---- h phase: wave e4 computes h for position base+e4
        {
            float a = b1s[j];
            if (p < pend) {
                const float* B = basis + (size_t)elist[p]*8;
                #pragma unroll
                for (int k = 0; k < NB; ++k) a = fmaf(B[k], W1s[k*HR + j], a);
            }
            hS[e4][j] = a / (1.f + expf(-a));
        }
        __syncthreads();
        // ---- dot phase: every thread dots all 4 positions' h with its 2 columns
        #pragma unroll
        for (int ee = 0; ee < CHUNK; ++ee) {
            const float4* hp4 = (const float4*)hS[ee];
            float r0 = 0.f, r1 = 0.f;
            #pragma unroll
            for (int jj = 0; jj < 16; ++jj) {
                float4 h4 = hp4[jj];
                r0 = fmaf(h4.x, w2r[4*jj+0].x, r0);
                r1 = fmaf(h4.x, w2r[4*jj+0].y, r1);
                r0 = fmaf(h4.y, w2r[4*jj+1].x, r0);
                r1 = fmaf(h4.y, w2r[4*jj+1].y, r1);
                r0 = fmaf(h4.z, w2r[4*jj+2].x, r0);
                r1 = fmaf(h4.z, w2r[4*jj+2].y, r1);
                r0 = fmaf(h4.w, w2r[4*jj+3].x, r0);
                r1 = fmaf(h4.w, w2r[4*jj+3].y, r1);
            }
            const int pg = base + ee;
            const int slot = pg - p0;
            if (pg < pend && slot < cap) rw2p[(size_t)slot*256 + t] = make_float2(r0, r1);
        }
        __syncthreads();   // protect hS before next iteration overwrites
    }
}

// ---------------- per-node: barrier-free edge aggregation + species linears + poly + readout ----------------
// node n = n0 + blockIdx.x; thread t: channel f=t&127, m-half mh=t>>7
__global__ __launch_bounds__(256) void k_agg(
    const int layer, const int n0,
    const int* __restrict__ spec_arr,
    const int* __restrict__ senders,
    const int* __restrict__ row_ptr,
    const int* __restrict__ elist,
    const float* __restrict__ sh,
    const float* __restrict__ rw,
    const float* __restrict__ linW,
    const float* __restrict__ prodc,
    const float* __restrict__ scW,
    const float* __restrict__ ro0,
    const float* __restrict__ ro1W1,
    const float* __restrict__ ro1W2,
    const float* __restrict__ scal_in,
    float* __restrict__ scal_out,
    float* __restrict__ feats,
    float* __restrict__ out)
{
    __shared__ float aggS[F*17];
    __shared__ float polyS[F];
    __shared__ float scalS[F];
    __shared__ float redS[F];

    const int t = threadIdx.x;
    const int n = n0 + blockIdx.x;
    const int f = t & 127;
    const int mh = t >> 7;

    const float4* rw4 = (const float4*)rw;
    const float4* sh4 = (const float4*)sh;

    float acc[8] = {0,0,0,0,0,0,0,0};
    const int p_base = row_ptr[n0];
    const int istart = row_ptr[n], iend = row_ptr[n+1];

    #pragma unroll 2
    for (int ii = istart; ii < iend; ++ii) {
        const int e = elist[ii];
        const int snd = senders[e];
        const int slot = ii - p_base;
        const float sf = scal_in[(size_t)snd*F + f];
        const float4 rwv = rw4[(size_t)slot*128 + f];
        const float4 shA = sh4[(size_t)e*4 + mh*2 + 0];
        const float4 shB = sh4[(size_t)e*4 + mh*2 + 1];
        if (mh == 0) {   // m=0..7, l=[0,1,1,1,2,2,2,2]
            const float a0 = sf*rwv.x, a1 = sf*rwv.y, a2 = sf*rwv.z;
            acc[0] = fmaf(a0, shA.x, acc[0]);
            acc[1] = fmaf(a1, shA.y, acc[1]);
            acc[2] = fmaf(a1, shA.z, acc[2]);
            acc[3] = fmaf(a1, shA.w, acc[3]);
            acc[4] = fmaf(a2, shB.x, acc[4]);
            acc[5] = fmaf(a2, shB.y, acc[5]);
            acc[6] = fmaf(a2, shB.z, acc[6]);
            acc[7] = fmaf(a2, shB.w, acc[7]);
        } else {         // m=8..15, l=[2,3,3,3,3,3,3,3]
            const float a2 = sf*rwv.z, a3 = sf*rwv.w;
            acc[0] = fmaf(a2, shA.x, acc[0]);
            acc[1] = fmaf(a3, shA.y, acc[1]);
            acc[2] = fmaf(a3, shA.z, acc[2]);
            acc[3] = fmaf(a3, shA.w, acc[3]);
            acc[4] = fmaf(a3, shB.x, acc[4]);
            acc[5] = fmaf(a3, shB.y, acc[5]);
            acc[6] = fmaf(a3, shB.z, acc[6]);
            acc[7] = fmaf(a3, shB.w, acc[7]);
        }
    }

    #pragma unroll
    for (int j = 0; j < 8; ++j) aggS[f*17 + mh*8 + j] = acc[j];
    __syncthreads();

    const int spec = spec_arr[n];
    const float* Wl = linW + (((size_t)layer*NSPEC + spec)*4) * F * F;

    float nv[8] = {0,0,0,0,0,0,0,0};
    if (mh == 0) {
        for (int f2 = 0; f2 < F; ++f2) {
            const float* ag = &aggS[f2*17];
            float w0  = Wl[(0*F + f2)*F + f];
            float w1  = Wl[(1*F + f2)*F + f];
            float w2v = Wl[(2*F + f2)*F + f];
            nv[0] = fmaf(ag[0], w0,  nv[0]);
            nv[1] = fmaf(ag[1], w1,  nv[1]);
            nv[2] = fmaf(ag[2], w1,  nv[2]);
            nv[3] = fmaf(ag[3], w1,  nv[3]);
            nv[4] = fmaf(ag[4], w2v, nv[4]);
            nv[5] = fmaf(ag[5], w2v, nv[5]);
            nv[6] = fmaf(ag[6], w2v, nv[6]);
            nv[7] = fmaf(ag[7], w2v, nv[7]);
        }
    } else {
        for (int f2 = 0; f2 < F; ++f2) {
            const float* ag = &aggS[f2*17 + 8];
            float w2v = Wl[(2*F + f2)*F + f];
            float w3  = Wl[(3*F + f2)*F + f];
            nv[0] = fmaf(ag[0], w2v, nv[0]);
            nv[1] = fmaf(ag[1], w3,  nv[1]);
            nv[2] = fmaf(ag[2], w3,  nv[2]);
            nv[3] = fmaf(ag[3], w3,  nv[3]);
            nv[4] = fmaf(ag[4], w3,  nv[4]);
            nv[5] = fmaf(ag[5], w3,  nv[5]);
            nv[6] = fmaf(ag[6], w3,  nv[6]);
            nv[7] = fmaf(ag[7], w3,  nv[7]);
        }
    }
    #pragma unroll
    for (int j = 0; j < 8; ++j) nv[j] *= 0.5f;  // EPS

    if (mh == 0) polyS[f] = nv[0];
    __syncthreads();
    const float* pc = prodc + ((size_t)layer*NSPEC + spec)*3*F;
    float sg = polyS[f];
    float poly = pc[f] + pc[F+f]*sg + pc[2*F+f]*sg*sg;

    float scv[8] = {0,0,0,0,0,0,0,0};
    if (layer > 0) {
        __syncthreads();  // all lin reads of aggS done
        {   // load old feats[n] -> aggS (padded layout), coalesced float4
            const float4* fp = (const float4*)(feats + (size_t)n*2048);
            float4 a = fp[t*2], b = fp[t*2 + 1];
            float tmp[8] = {a.x,a.y,a.z,a.w,b.x,b.y,b.z,b.w};
            #pragma unroll
            for (int k = 0; k < 8; ++k) {
                int q = t*8 + k;
                aggS[(q >> 4)*17 + (q & 15)] = tmp[k];
            }
        }
        __syncthreads();
        const float* Ws = scW + (((size_t)layer*NSPEC + spec)*4) * F * F;
        if (mh == 0) {
            for (int f2 = 0; f2 < F; ++f2) {
                const float* ag = &aggS[f2*17];
                float w0  = Ws[(0*F + f2)*F + f];
                float w1  = Ws[(1*F + f2)*F + f];
                float w2v = Ws[(2*F + f2)*F + f];
                scv[0] = fmaf(ag[0], w0,  scv[0]);
                scv[1] = fmaf(ag[1], w1,  scv[1]);
                scv[2] = fmaf(ag[2], w1,  scv[2]);
                scv[3] = fmaf(ag[3], w1,  scv[3]);
                scv[4] = fmaf(ag[4], w2v, scv[4]);
                scv[5] = fmaf(ag[5], w2v, scv[5]);
                scv[6] = fmaf(ag[6], w2v, scv[6]);
                scv[7] = fmaf(ag[7], w2v, scv[7]);
            }
        } else {
            for (int f2 = 0; f2 < F; ++f2) {
                const float* ag = &aggS[f2*17 + 8];
                float w2v = Ws[(2*F + f2)*F + f];
                float w3  = Ws[(3*F + f2)*F + f];
                scv[0] = fmaf(ag[0], w2v, scv[0]);
                scv[1] = fmaf(ag[1], w3,  scv[1]);
                scv[2] = fmaf(ag[2], w3,  scv[2]);
                scv[3] = fmaf(ag[3], w3,  scv[3]);
                scv[4] = fmaf(ag[4], w3,  scv[4]);
                scv[5] = fmaf(ag[5], w3,  scv[5]);
                scv[6] = fmaf(ag[6], w3,  scv[6]);
                scv[7] = fmaf(ag[7], w3,  scv[7]);
            }
        }
    }

    float ov[8];
    #pragma unroll
    for (int j = 0; j < 8; ++j) ov[j] = fmaf(nv[j], poly, scv[j]);

    {   // write new feats[n, f, mh*8 + 0..7]
        float4* wp = (float4*)(feats + (size_t)n*2048 + f*16 + mh*8);
        wp[0] = make_float4(ov[0], ov[1], ov[2], ov[3]);
        wp[1] = make_float4(ov[4], ov[5], ov[6], ov[7]);
    }
    if (mh == 0) { scal_out[n*F + f] = ov[0]; scalS[f] = ov[0]; }
    __syncthreads();

    if (layer == 0) {
        if (t < 128) redS[t] = scalS[t] * ro0[t];
        __syncthreads();
        for (int off = 64; off > 0; off >>= 1) {
            if (t < off) redS[t] += redS[t + off];
            __syncthreads();
        }
        if (t == 0) out[n*2 + 0] = redS[0];
    } else {
        if (t < 16) {
            float a = 0.f;
            for (int g = 0; g < F; ++g) a = fmaf(scalS[g], ro1W1[g*16 + t], a);
            a = silu_f(a);
            redS[t] = a * ro1W2[t];
        }
        __syncthreads();
        if (t == 0) {
            float s2 = 0.f;
            #pragma unroll
            for (int j = 0; j < 16; ++j) s2 += redS[j];
            out[n*2 + 1] = s2;
        }
    }
}

extern "C" void kernel_launch(void* const* d_in, const int* in_sizes, int n_in,
                              void* d_out, int out_size, void* d_ws, size_t ws_size,
                              hipStream_t stream)
{
    (void)in_sizes; (void)n_in; (void)out_size;
    const float* vectors   = (const float*)d_in[0];
    const int*   spec      = (const int*)d_in[1];
    const int*   senders   = (const int*)d_in[2];
    const int*   receivers = (const int*)d_in[3];
    const float* embW      = (const float*)d_in[4];
    const float* rW1       = (const float*)d_in[5];
    const float* rb1       = (const float*)d_in[6];
    const float* rW2       = (const float*)d_in[7];
    const float* linW      = (const float*)d_in[8];
    const float* prodc     = (const float*)d_in[9];
    const float* scW       = (const float*)d_in[10];
    const float* ro0       = (const float*)d_in[11];
    const float* ro1W1     = (const float*)d_in[12];
    const float* ro1W2     = (const float*)d_in[13];
    float* out = (float*)d_out;

    char* ws = (char*)d_ws;
    float* sh      = (float*)ws; ws += sizeof(float)*(size_t)N_EDGES*16;
    float* basis   = (float*)ws; ws += sizeof(float)*(size_t)N_EDGES*8;
    float* scalA   = (float*)ws; ws += sizeof(float)*(size_t)N_NODES*F;
    float* scalB   = (float*)ws; ws += sizeof(float)*(size_t)N_NODES*F;
    float* feats   = (float*)ws; ws += sizeof(float)*(size_t)N_NODES*F*16;
    int*   row_ptr = (int*)ws;   ws += sizeof(int)*(N_NODES+1);
    int*   counts  = (int*)ws;   ws += sizeof(int)*N_NODES;
    int*   cursor  = (int*)ws;   ws += sizeof(int)*N_NODES;
    int*   elist   = (int*)ws;   ws += sizeof(int)*N_EDGES;

    // rw chunk buffer: everything that's left, 256B-aligned
    uintptr_t rwa = ((uintptr_t)ws + 255) & ~(uintptr_t)255;
    float* rw = (float*)rwa;
    size_t used = (size_t)(rwa - (uintptr_t)d_ws);
    size_t avail = (ws_size > used) ? (ws_size - used) : 0;

    // pick smallest chunk count whose capacity fits:
    // cap(npc) = expected positions (16*npc) + slack (npc/4 + 2048), each position = 512 floats
    static const int cands[] = {1, 2, 4, 5, 8, 10, 16, 20, 25, 40, 50, 80, 100, 125, 200, 250, 500};
    int nch = 0, npc = 0; long long cap = 0;
    for (int idx = 0; idx < (int)(sizeof(cands)/sizeof(cands[0])); ++idx) {
        int c = cands[idx];
        int np = N_NODES / c;
        long long cp = (c == 1) ? (long long)N_EDGES
                                : (long long)16*np + np/4 + 2048;
        if (cp > N_EDGES) cp = N_EDGES;
        if ((unsigned long long)cp * 2048ull <= (unsigned long long)avail) {
            nch = c; npc = np; cap = cp; break;
        }
    }
    if (nch == 0) { nch = 500; npc = 20; cap = (long long)(avail / 2048); }  // degenerate fallback

    hipMemsetAsync(counts, 0, sizeof(int)*2*N_NODES, stream);  // counts + cursor (contiguous)

    k_edge_pre<<<(N_EDGES+255)/256, 256, 0, stream>>>(vectors, receivers, sh, basis, counts);
    k_scan<<<1, 1024, 0, stream>>>(counts, row_ptr);
    k_fill<<<(N_EDGES+255)/256, 256, 0, stream>>>(receivers, row_ptr, cursor, elist);
    k_init_scal<<<(N_NODES*F+255)/256, 256, 0, stream>>>(spec, embW, scalA);

    int gridR = (int)((cap + CHUNK - 1) / CHUNK);
    if (gridR > 2048) gridR = 2048;
    if (gridR < 1) gridR = 1;

    for (int layer = 0; layer < 2; ++layer) {
        const float* s_in  = (layer == 0) ? scalA : scalB;
        float*       s_out = (layer == 0) ? scalB : scalA;
        for (int c = 0; c < nch; ++c) {
            int n0 = c * npc, n1 = n0 + npc;
            k_radial<<<gridR, 256, 0, stream>>>(layer, n0, n1, (int)cap,
                row_ptr, elist, basis, rW1, rb1, rW2, rw);
            k_agg<<<npc, 256, 0, stream>>>(layer, n0, spec, senders, row_ptr, elist, sh, rw,
                linW, prodc, scW, ro0, ro1W1, ro1W2, s_in, s_out, feats, out);
        }
    }
}

// Round 5
// 1222.097 us; speedup vs baseline: 1.5467x; 1.0344x over previous
//
#include <hip/hip_runtime.h>
#include <math.h>
#include <stdint.h>

#define N_NODES 10000
#define N_EDGES 160000
#define F 128
#define NB 8
#define HR 64
#define NSPEC 10
#define PI_F 3.14159265358979323846f
#define CHUNK 4

__device__ __forceinline__ float silu_f(float x){ return x / (1.f + expf(-x)); }

// ---------------- receiver histogram ----------------
__global__ void k_count(const int* __restrict__ recv, int* __restrict__ counts)
{
    int e = blockIdx.x * 256 + threadIdx.x;
    if (e >= N_EDGES) return;
    atomicAdd(&counts[recv[e]], 1);
}

// ---------------- block-wide scan -> row_ptr ----------------
__global__ void k_scan(const int* __restrict__ counts, int* __restrict__ row_ptr)
{
    __shared__ int ps[1024];
    const int t = threadIdx.x;
    int base = t * 10;
    int loc[10];
    int sum = 0;
    #pragma unroll
    for (int j = 0; j < 10; ++j) {
        int idx = base + j;
        int c = (idx < N_NODES) ? counts[idx] : 0;
        loc[j] = c; sum += c;
    }
    ps[t] = sum;
    __syncthreads();
    for (int off = 1; off < 1024; off <<= 1) {
        int v = (t >= off) ? ps[t-off] : 0;
        __syncthreads();
        ps[t] += v;
        __syncthreads();
    }
    int ex = ps[t] - sum;
    #pragma unroll
    for (int j = 0; j < 10; ++j) {
        int idx = base + j;
        if (idx < N_NODES) row_ptr[idx] = ex;
        ex += loc[j];
    }
    if (t == 1023) row_ptr[N_NODES] = ex;
}

// ---------------- fill CSR edge list ----------------
__global__ void k_fill(const int* __restrict__ recv, const int* __restrict__ row_ptr,
                       int* __restrict__ cursor, int* __restrict__ elist)
{
    int e = blockIdx.x * 256 + threadIdx.x;
    if (e >= N_EDGES) return;
    int r = recv[e];
    int pos = atomicAdd(&cursor[r], 1);
    elist[row_ptr[r] + pos] = e;
}

// ---------------- position-order edge precompute: sh_pos[p,16], basis_pos[p,8], snd_pos[p] ----------------
__global__ void k_edge_pre(const int* __restrict__ elist, const int* __restrict__ senders,
                           const float* __restrict__ vec,
                           float* __restrict__ sh_pos, float* __restrict__ basis_pos,
                           int* __restrict__ snd_pos)
{
    int p = blockIdx.x * 256 + threadIdx.x;
    if (p >= N_EDGES) return;
    const int e = elist[p];
    snd_pos[p] = senders[e];
    float x = vec[e*3+0], y = vec[e*3+1], z = vec[e*3+2];
    float r = sqrtf(x*x + y*y + z*z);
    r = fmaxf(r, 1e-9f);
    float inv = 1.f / r;
    x *= inv; y *= inv; z *= inv;
    const float s3=1.7320508075688772f, s5=2.23606797749979f, s7=2.6457513110645907f,
                s15=3.872983346207417f, s42=6.480740698407860f, s70=8.366600265340756f,
                s105=10.246950765959598f;
    float* S = sh_pos + (size_t)p*16;
    S[0]=1.f; S[1]=s3*x; S[2]=s3*y; S[3]=s3*z;
    S[4]=s15*x*y; S[5]=s15*y*z; S[6]=0.5f*s5*(3.f*z*z-1.f); S[7]=s15*x*z;
    S[8]=0.5f*s15*(x*x-y*y);
    S[9]=0.25f*s70*y*(3.f*x*x-y*y); S[10]=s105*x*y*z; S[11]=0.25f*s42*y*(5.f*z*z-1.f);
    S[12]=0.5f*s7*(5.f*z*z*z-3.f*z); S[13]=0.25f*s42*x*(5.f*z*z-1.f);
    S[14]=0.5f*s105*z*(x*x-y*y); S[15]=0.25f*s70*x*(x*x-3.f*y*y);
    float rc = fminf(r, 5.0f);
    float cut = 0.5f * (cosf(PI_F * rc * 0.2f) + 1.f);
    float pref = sqrtf(0.4f) * cut / r;
    float* B = basis_pos + (size_t)p*8;
    #pragma unroll
    for (int k = 1; k <= 8; ++k) B[k-1] = pref * sinf(PI_F * 0.2f * (float)k * r);
}

// ---------------- init scalA (N,F) = emb ----------------
__global__ void k_init_scal(const int* __restrict__ spec, const float* __restrict__ embW,
                            float* __restrict__ scalA)
{
    int tid = blockIdx.x * 256 + threadIdx.x;
    if (tid >= N_NODES * F) return;
    int n = tid >> 7, f = tid & 127;
    scalA[tid] = embW[spec[n]*F + f];
}

// ---------------- radial MLP over CSR-position window: rw[slot,512] ----------------
// positions p in [row_ptr[n0], row_ptr[n1]); rw slot = p - row_ptr[n0]
__global__ __launch_bounds__(256) void k_radial(
    const int layer, const int n0, const int n1, const int cap,
    const int* __restrict__ row_ptr,
    const float* __restrict__ basis_pos,
    const float* __restrict__ rW1,
    const float* __restrict__ rb1,
    const float* __restrict__ rW2,
    float* __restrict__ rw)
{
    __shared__ float W1s[NB*HR];
    __shared__ float b1s[HR];
    __shared__ float hS[CHUNK][HR];

    const int t = threadIdx.x;
    W1s[t] = rW1[layer*NB*HR + t];
    W1s[256 + t] = rW1[layer*NB*HR + 256 + t];
    if (t < HR) b1s[t] = rb1[layer*HR + t];

    const float2* W2g = (const float2*)(rW2 + (size_t)layer*HR*512);
    float2 w2r[64];
    #pragma unroll
    for (int j = 0; j < 64; ++j) w2r[j] = W2g[j*256 + t];

    const int p0   = row_ptr[n0];
    const int pend = row_ptr[n1];
    const int e4 = t >> 6, j = t & 63;
    float2* rw2p = (float2*)rw;
    const int stride = gridDim.x * CHUNK;

    __syncthreads();
    for (int base = p0 + blockIdx.x * CHUNK; base < pend; base += stride) {
        const int p = base + e4;
        // ---- h phase: wave e4 computes h for position base+e4 (contiguous basis read)
        {
            float a = b1s[j];
            if (p < pend) {
                const float4* B4 = (const float4*)(basis_pos + (size_t)p*8);
                float4 b0 = B4[0], b1v = B4[1];
                a = fmaf(b0.x, W1s[0*HR + j], a);
                a = fmaf(b0.y, W1s[1*HR + j], a);
                a = fmaf(b0.z, W1s[2*HR + j], a);
                a = fmaf(b0.w, W1s[3*HR + j], a);
                a = fmaf(b1v.x, W1s[4*HR + j], a);
                a = fmaf(b1v.y, W1s[5*HR + j], a);
                a = fmaf(b1v.z, W1s[6*HR + j], a);
                a = fmaf(b1v.w, W1s[7*HR + j], a);
            }
            hS[e4][j] = a / (1.f + expf(-a));
        }
        __syncthreads();
        // ---- dot phase: every thread dots all 4 positions' h with its 2 columns
        #pragma unroll
        for (int ee = 0; ee < CHUNK; ++ee) {
            const float4* hp4 = (const float4*)hS[ee];
            float r0 = 0.f, r1 = 0.f;
            #pragma unroll
            for (int jj = 0; jj < 16; ++jj) {
                float4 h4 = hp4[jj];
                r0 = fmaf(h4.x, w2r[4*jj+0].x, r0);
                r1 = fmaf(h4.x, w2r[4*jj+0].y, r1);
                r0 = fmaf(h4.y, w2r[4*jj+1].x, r0);
                r1 = fmaf(h4.y, w2r[4*jj+1].y, r1);
                r0 = fmaf(h4.z, w2r[4*jj+2].x, r0);
                r1 = fmaf(h4.z, w2r[4*jj+2].y, r1);
                r0 = fmaf(h4.w, w2r[4*jj+3].x, r0);
                r1 = fmaf(h4.w, w2r[4*jj+3].y, r1);
            }
            const int pg = base + ee;
            const int slot = pg - p0;
            if (pg < pend && slot < cap) rw2p[(size_t)slot*256 + t] = make_float2(r0, r1);
        }
        __syncthreads();   // protect hS before next iteration overwrites
    }
}

// ---------------- per-node: streaming edge aggregation + merged species linears + poly + readout ----------------
// node n = n0 + blockIdx.x; thread t: channel f=t&127, m-half mh=t>>7
__global__ __launch_bounds__(256) void k_agg(
    const int layer, const int n0,
    const int* __restrict__ spec_arr,
    const int* __restrict__ row_ptr,
    const int* __restrict__ snd_pos,
    const float* __restrict__ sh_pos,
    const float* __restrict__ rw,
    const float* __restrict__ linW,
    const float* __restrict__ prodc,
    const float* __restrict__ scW,
    const float* __restrict__ ro0,
    const float* __restrict__ ro1W1,
    const float* __restrict__ ro1W2,
    const float* __restrict__ scal_in,
    float* __restrict__ scal_out,
    float* __restrict__ feats,
    float* __restrict__ out)
{
    __shared__ float aggS[F*17];
    __shared__ float ftS[F*17];
    __shared__ float polyS[F];
    __shared__ float scalS[F];
    __shared__ float redS[F];

    const int t = threadIdx.x;
    const int n = n0 + blockIdx.x;
    const int f = t & 127;
    const int mh = t >> 7;

    const float4* rw4 = (const float4*)rw;
    const float4* sh4 = (const float4*)sh_pos;

    float acc[8] = {0,0,0,0,0,0,0,0};
    const int p_base = row_ptr[n0];
    const int istart = row_ptr[n], iend = row_ptr[n+1];

    #pragma unroll 4
    for (int ii = istart; ii < iend; ++ii) {
        const int snd = snd_pos[ii];                      // uniform -> scalar load
        const float sf = scal_in[(size_t)snd*F + f];      // single gather (chain depth 2)
        const float4 rwv = rw4[(size_t)(ii - p_base)*128 + f];  // streaming
        const float4 shA = sh4[(size_t)ii*4 + mh*2 + 0];        // streaming broadcast
        const float4 shB = sh4[(size_t)ii*4 + mh*2 + 1];
        if (mh == 0) {   // m=0..7, l=[0,1,1,1,2,2,2,2]
            const float a0 = sf*rwv.x, a1 = sf*rwv.y, a2 = sf*rwv.z;
            acc[0] = fmaf(a0, shA.x, acc[0]);
            acc[1] = fmaf(a1, shA.y, acc[1]);
            acc[2] = fmaf(a1, shA.z, acc[2]);
            acc[3] = fmaf(a1, shA.w, acc[3]);
            acc[4] = fmaf(a2, shB.x, acc[4]);
            acc[5] = fmaf(a2, shB.y, acc[5]);
            acc[6] = fmaf(a2, shB.z, acc[6]);
            acc[7] = fmaf(a2, shB.w, acc[7]);
        } else {         // m=8..15, l=[2,3,3,3,3,3,3,3]
            const float a2 = sf*rwv.z, a3 = sf*rwv.w;
            acc[0] = fmaf(a2, shA.x, acc[0]);
            acc[1] = fmaf(a3, shA.y, acc[1]);
            acc[2] = fmaf(a3, shA.z, acc[2]);
            acc[3] = fmaf(a3, shA.w, acc[3]);
            acc[4] = fmaf(a3, shB.x, acc[4]);
            acc[5] = fmaf(a3, shB.y, acc[5]);
            acc[6] = fmaf(a3, shB.z, acc[6]);
            acc[7] = fmaf(a3, shB.w, acc[7]);
        }
    }

    #pragma unroll
    for (int j = 0; j < 8; ++j) aggS[f*17 + mh*8 + j] = acc[j];
    if (layer > 0) {   // stage old feats[n] -> ftS (padded layout), coalesced float4
        const float4* fp = (const float4*)(feats + (size_t)n*2048);
        float4 a = fp[t*2], b = fp[t*2 + 1];
        float tmp[8] = {a.x,a.y,a.z,a.w,b.x,b.y,b.z,b.w};
        #pragma unroll
        for (int k = 0; k < 8; ++k) {
            int q = t*8 + k;
            ftS[(q >> 4)*17 + (q & 15)] = tmp[k];
        }
    }
    __syncthreads();

    const int spec = spec_arr[n];
    const float* Wl = linW + (((size_t)layer*NSPEC + spec)*4) * F * F;
    const float* Ws = scW  + (((size_t)layer*NSPEC + spec)*4) * F * F;

    float nv[8] = {0,0,0,0,0,0,0,0};
    float scv[8] = {0,0,0,0,0,0,0,0};

    if (layer == 0) {
        if (mh == 0) {
            #pragma unroll 4
            for (int f2 = 0; f2 < F; ++f2) {
                const float* ag = &aggS[f2*17];
                float w0  = Wl[(0*F + f2)*F + f];
                float w1  = Wl[(1*F + f2)*F + f];
                float w2v = Wl[(2*F + f2)*F + f];
                nv[0] = fmaf(ag[0], w0,  nv[0]);
                nv[1] = fmaf(ag[1], w1,  nv[1]);
                nv[2] = fmaf(ag[2], w1,  nv[2]);
                nv[3] = fmaf(ag[3], w1,  nv[3]);
                nv[4] = fmaf(ag[4], w2v, nv[4]);
                nv[5] = fmaf(ag[5], w2v, nv[5]);
                nv[6] = fmaf(ag[6], w2v, nv[6]);
                nv[7] = fmaf(ag[7], w2v, nv[7]);
            }
        } else {
            #pragma unroll 4
            for (int f2 = 0; f2 < F; ++f2) {
                const float* ag = &aggS[f2*17 + 8];
                float w2v = Wl[(2*F + f2)*F + f];
                float w3  = Wl[(3*F + f2)*F + f];
                nv[0] = fmaf(ag[0], w2v, nv[0]);
                nv[1] = fmaf(ag[1], w3,  nv[1]);
                nv[2] = fmaf(ag[2], w3,  nv[2]);
                nv[3] = fmaf(ag[3], w3,  nv[3]);
                nv[4] = fmaf(ag[4], w3,  nv[4]);
                nv[5] = fmaf(ag[5], w3,  nv[5]);
                nv[6] = fmaf(ag[6], w3,  nv[6]);
                nv[7] = fmaf(ag[7], w3,  nv[7]);
            }
        }
    } else {
        // merged lin + sc pass: 6 weight loads + 16 FMAs per f2
        if (mh == 0) {
            #pragma unroll 4
            for (int f2 = 0; f2 < F; ++f2) {
                const float* ag = &aggS[f2*17];
                const float* ft = &ftS[f2*17];
                float w0  = Wl[(0*F + f2)*F + f];
                float w1  = Wl[(1*F + f2)*F + f];
                float w2v = Wl[(2*F + f2)*F + f];
                float u0  = Ws[(0*F + f2)*F + f];
                float u1  = Ws[(1*F + f2)*F + f];
                float u2v = Ws[(2*F + f2)*F + f];
                nv[0] = fmaf(ag[0], w0,  nv[0]);
                nv[1] = fmaf(ag[1], w1,  nv[1]);
                nv[2] = fmaf(ag[2], w1,  nv[2]);
                nv[3] = fmaf(ag[3], w1,  nv[3]);
                nv[4] = fmaf(ag[4], w2v, nv[4]);
                nv[5] = fmaf(ag[5], w2v, nv[5]);
                nv[6] = fmaf(ag[6], w2v, nv[6]);
                nv[7] = fmaf(ag[7], w2v, nv[7]);
                scv[0] = fmaf(ft[0], u0,  scv[0]);
                scv[1] = fmaf(ft[1], u1,  scv[1]);
                scv[2] = fmaf(ft[2], u1,  scv[2]);
                scv[3] = fmaf(ft[3], u1,  scv[3]);
                scv[4] = fmaf(ft[4], u2v, scv[4]);
                scv[5] = fmaf(ft[5], u2v, scv[5]);
                scv[6] = fmaf(ft[6], u2v, scv[6]);
                scv[7] = fmaf(ft[7], u2v, scv[7]);
            }
        } else {
            #pragma unroll 4
            for (int f2 = 0; f2 < F; ++f2) {
                const float* ag = &aggS[f2*17 + 8];
                const float* ft = &ftS[f2*17 + 8];
                float w2v = Wl[(2*F + f2)*F + f];
                float w3  = Wl[(3*F + f2)*F + f];
                float u2v = Ws[(2*F + f2)*F + f];
                float u3  = Ws[(3*F + f2)*F + f];
                nv[0] = fmaf(ag[0], w2v, nv[0]);
                nv[1] = fmaf(ag[1], w3,  nv[1]);
                nv[2] = fmaf(ag[2], w3,  nv[2]);
                nv[3] = fmaf(ag[3], w3,  nv[3]);
                nv[4] = fmaf(ag[4], w3,  nv[4]);
                nv[5] = fmaf(ag[5], w3,  nv[5]);
                nv[6] = fmaf(ag[6], w3,  nv[6]);
                nv[7] = fmaf(ag[7], w3,  nv[7]);
                scv[0] = fmaf(ft[0], u2v, scv[0]);
                scv[1] = fmaf(ft[1], u3,  scv[1]);
                scv[2] = fmaf(ft[2], u3,  scv[2]);
                scv[3] = fmaf(ft[3], u3,  scv[3]);
                scv[4] = fmaf(ft[4], u3,  scv[4]);
                scv[5] = fmaf(ft[5], u3,  scv[5]);
                scv[6] = fmaf(ft[6], u3,  scv[6]);
                scv[7] = fmaf(ft[7], u3,  scv[7]);
            }
        }
    }
    #pragma unroll
    for (int j = 0; j < 8; ++j) nv[j] *= 0.5f;  // EPS

    if (mh == 0) polyS[f] = nv[0];
    __syncthreads();
    const float* pc = prodc + ((size_t)layer*NSPEC + spec)*3*F;
    float sg = polyS[f];
    float poly = pc[f] + pc[F+f]*sg + pc[2*F+f]*sg*sg;

    float ov[8];
    #pragma unroll
    for (int j = 0; j < 8; ++j) ov[j] = fmaf(nv[j], poly, scv[j]);

    {   // write new feats[n, f, mh*8 + 0..7]
        float4* wp = (float4*)(feats + (size_t)n*2048 + f*16 + mh*8);
        wp[0] = make_float4(ov[0], ov[1], ov[2], ov[3]);
        wp[1] = make_float4(ov[4], ov[5], ov[6], ov[7]);
    }
    if (mh == 0) { scal_out[n*F + f] = ov[0]; scalS[f] = ov[0]; }
    __syncthreads();

    if (layer == 0) {
        if (t < 128) redS[t] = scalS[t] * ro0[t];
        __syncthreads();
        for (int off = 64; off > 0; off >>= 1) {
            if (t < off) redS[t] += redS[t + off];
            __syncthreads();
        }
        if (t == 0) out[n*2 + 0] = redS[0];
    } else {
        if (t < 16) {
            float a = 0.f;
            for (int g = 0; g < F; ++g) a = fmaf(scalS[g], ro1W1[g*16 + t], a);
            a = silu_f(a);
            redS[t] = a * ro1W2[t];
        }
        __syncthreads();
        if (t == 0) {
            float s2 = 0.f;
            #pragma unroll
            for (int j = 0; j < 16; ++j) s2 += redS[j];
            out[n*2 + 1] = s2;
        }
    }
}

extern "C" void kernel_launch(void* const* d_in, const int* in_sizes, int n_in,
                              void* d_out, int out_size, void* d_ws, size_t ws_size,
                              hipStream_t stream)
{
    (void)in_sizes; (void)n_in; (void)out_size;
    const float* vectors   = (const float*)d_in[0];
    const int*   spec      = (const int*)d_in[1];
    const int*   senders   = (const int*)d_in[2];
    const int*   receivers = (const int*)d_in[3];
    const float* embW      = (const float*)d_in[4];
    const float* rW1       = (const float*)d_in[5];
    const float* rb1       = (const float*)d_in[6];
    const float* rW2       = (const float*)d_in[7];
    const float* linW      = (const float*)d_in[8];
    const float* prodc     = (const float*)d_in[9];
    const float* scW       = (const float*)d_in[10];
    const float* ro0       = (const float*)d_in[11];
    const float* ro1W1     = (const float*)d_in[12];
    const float* ro1W2     = (const float*)d_in[13];
    float* out = (float*)d_out;

    char* ws = (char*)d_ws;
    float* scalA     = (float*)ws; ws += sizeof(float)*(size_t)N_NODES*F;
    float* scalB     = (float*)ws; ws += sizeof(float)*(size_t)N_NODES*F;
    float* feats     = (float*)ws; ws += sizeof(float)*(size_t)N_NODES*F*16;
    float* sh_pos    = (float*)ws; ws += sizeof(float)*(size_t)N_EDGES*16;
    float* basis_pos = (float*)ws; ws += sizeof(float)*(size_t)N_EDGES*8;
    int*   snd_pos   = (int*)ws;   ws += sizeof(int)*N_EDGES;
    int*   row_ptr   = (int*)ws;   ws += sizeof(int)*(N_NODES+1);
    int*   counts    = (int*)ws;   ws += sizeof(int)*N_NODES;
    int*   cursor    = (int*)ws;   ws += sizeof(int)*N_NODES;
    int*   elist     = (int*)ws;   ws += sizeof(int)*N_EDGES;

    // rw chunk buffer: everything that's left, 256B-aligned
    uintptr_t rwa = ((uintptr_t)ws + 255) & ~(uintptr_t)255;
    float* rw = (float*)rwa;
    size_t used = (size_t)(rwa - (uintptr_t)d_ws);
    size_t avail = (ws_size > used) ? (ws_size - used) : 0;

    // pick smallest chunk count whose capacity fits:
    // cap(npc) = expected positions (16*npc) + slack (npc/4 + 2048), each position = 512 floats
    static const int cands[] = {1, 2, 4, 5, 8, 10, 16, 20, 25, 40, 50, 80, 100, 125, 200, 250, 500};
    int nch = 0, npc = 0; long long cap = 0;
    for (int idx = 0; idx < (int)(sizeof(cands)/sizeof(cands[0])); ++idx) {
        int c = cands[idx];
        int np = N_NODES / c;
        long long cp = (c == 1) ? (long long)N_EDGES
                                : (long long)16*np + np/4 + 2048;
        if (cp > N_EDGES) cp = N_EDGES;
        if ((unsigned long long)cp * 2048ull <= (unsigned long long)avail) {
            nch = c; npc = np; cap = cp; break;
        }
    }
    if (nch == 0) { nch = 500; npc = 20; cap = (long long)(avail / 2048); }  // degenerate fallback

    hipMemsetAsync(counts, 0, sizeof(int)*2*N_NODES, stream);  // counts + cursor (contiguous)

    k_count<<<(N_EDGES+255)/256, 256, 0, stream>>>(receivers, counts);
    k_scan<<<1, 1024, 0, stream>>>(counts, row_ptr);
    k_fill<<<(N_EDGES+255)/256, 256, 0, stream>>>(receivers, row_ptr, cursor, elist);
    k_edge_pre<<<(N_EDGES+255)/256, 256, 0, stream>>>(elist, senders, vectors, sh_pos, basis_pos, snd_pos);
    k_init_scal<<<(N_NODES*F+255)/256, 256, 0, stream>>>(spec, embW, scalA);

    int gridR = (int)((cap + CHUNK - 1) / CHUNK);
    if (gridR > 2048) gridR = 2048;
    if (gridR < 1) gridR = 1;

    for (int layer = 0; layer < 2; ++layer) {
        const float* s_in  = (layer == 0) ? scalA : scalB;
        float*       s_out = (layer == 0) ? scalB : scalA;
        for (int c = 0; c < nch; ++c) {
            int n0 = c * npc, n1 = n0 + npc;
            k_radial<<<gridR, 256, 0, stream>>>(layer, n0, n1, (int)cap,
                row_ptr, basis_pos, rW1, rb1, rW2, rw);
            k_agg<<<npc, 256, 0, stream>>>(layer, n0, spec, row_ptr, snd_pos, sh_pos, rw,
                linW, prodc, scW, ro0, ro1W1, ro1W2, s_in, s_out, feats, out);
        }
    }
}